// Round 8
// baseline (654.924 us; speedup 1.0000x reference)
//
#include <hip/hip_runtime.h>
#include <hip/hip_bf16.h>
#include <stdint.h>

// Problem constants
#define B_M 512
#define D_K 512
#define C_N 100000
#define S_SCALE 64.0f
#define W_LOSS 0.003f
#define COS_M_C 0.79608379854905604f
#define SIN_M_C 0.60518640573603957f
#define THRESH_C (-0.79608379854905604f)
#define MM_C 0.39337116372842573f

typedef __bf16 bf16x8 __attribute__((ext_vector_type(8)));
typedef float f32x4 __attribute__((ext_vector_type(4)));

typedef const __attribute__((address_space(1))) unsigned char* gptr_t;
typedef __attribute__((address_space(3))) unsigned char* sptr_t;

__device__ __forceinline__ unsigned short f2bf(float f) {
  __bf16 h = (__bf16)f;
  return __builtin_bit_cast(unsigned short, h);
}

// ---------------------------------------------------------------------------
// Kernel 1: normalize emb rows (f32), write swizzled bf16 A-tiles to ws,
// compute target_logit[b] exactly in f32.
// wsA layout: 32 tiles (mq 0..3  x  ktile 0..7) of 16 KB;
// tile = [128 rows][128 B], byte-in-row XOR ((row&7)<<4)  (LDS image).
// ---------------------------------------------------------------------------
__global__ __launch_bounds__(256) void prep_kernel(
    const float* __restrict__ emb, const float* __restrict__ Kg,
    const int* __restrict__ label, unsigned char* __restrict__ wsA,
    float* __restrict__ tl)
{
  int b = blockIdx.x, t = threadIdx.x;
  __shared__ float row[512];
  __shared__ float r1[256], r2[256];

  float2 v = ((const float2*)(emb + (size_t)b * 512))[t];
  r1[t] = v.x * v.x + v.y * v.y;
  __syncthreads();
  for (int s = 128; s > 0; s >>= 1) {
    if (t < s) r1[t] += r1[t + s];
    __syncthreads();
  }
  float inv = 1.0f / sqrtf(r1[0]);
  float e0 = v.x * inv, e1 = v.y * inv;
  row[2 * t] = e0;
  row[2 * t + 1] = e1;

  {
    int mq = b >> 7, lrow = b & 127;
    int kk = t >> 5;  // (2t)/64 : k-tile index
    int byte_in = (4 * (t & 31)) ^ ((lrow & 7) << 4);
    ushort2 h;
    h.x = f2bf(e0);
    h.y = f2bf(e1);
    *(ushort2*)(wsA + (size_t)(mq * 8 + kk) * 16384 + lrow * 128 + byte_in) = h;
  }
  __syncthreads();

  int lab = label[b];
  const float* kc = Kg + lab;
  float dot = 0.f, csq = 0.f;
  for (int d = t; d < 512; d += 256) {
    float kv = kc[(size_t)d * C_N];
    dot += row[d] * kv;
    csq += kv * kv;
  }
  r1[t] = dot;
  r2[t] = csq;
  __syncthreads();
  for (int s = 128; s > 0; s >>= 1) {
    if (t < s) { r1[t] += r1[t + s]; r2[t] += r2[t + s]; }
    __syncthreads();
  }
  if (t == 0) {
    float tlv = r1[0] / sqrtf(r2[0]);
    tl[b] = fminf(1.f, fmaxf(-1.f, tlv));
  }
}

// ---------------------------------------------------------------------------
// Kernel 2: t_new, cos_theta_m[b], final_target_logit[b], center-loss scalar.
// ---------------------------------------------------------------------------
__global__ __launch_bounds__(512) void finalize_kernel(
    const float* __restrict__ tl, const float* __restrict__ t_in,
    float* __restrict__ ctm, float* __restrict__ ftl,
    float* __restrict__ tnew, float* __restrict__ out3)
{
  int t = threadIdx.x;
  float v = tl[t];
  __shared__ float r1[512], r2[512];
  float ac = acosf(v);
  r1[t] = v;
  r2[t] = ac * sqrtf(ac);  // acos^1.5
  __syncthreads();
  for (int s = 256; s > 0; s >>= 1) {
    if (t < s) { r1[t] += r1[t + s]; r2[t] += r2[t + s]; }
    __syncthreads();
  }
  if (t == 0) {
    tnew[0] = 0.99f * t_in[0] + 0.01f * (r1[0] / 512.0f);
    out3[0] = S_SCALE * W_LOSS * (r2[0] / 512.0f);
  }
  float st = sqrtf(fmaxf(0.f, 1.f - v * v));
  float cm = v * COS_M_C - st * SIN_M_C;
  ctm[t] = cm;
  ftl[t] = (v > THRESH_C) ? cm : (v - MM_C);
}

// ---------------------------------------------------------------------------
// Kernel 3: fused GEMM + epilogue, 3-blocks/CU shape.
// BM=128, BN=128, BK=64; 512 threads, 8 waves (2M x 4N), wave tile 64x32.
// A single-buffer LDS (16KB), staged per step via 2 gll/thread from the
// L2-resident ws image. B single 16KB buffer, 1-step register prefetch
// (bf[16]); counted vmcnt(16) retires the 2 A-DMAs, keeps B[k+1] in flight.
// LDS 36.8KB; reg target <=85 total -> __launch_bounds__(512,6): 3 blocks.
// Epilogue: acc -> LDS (f32, XOR-swizzled) -> 512B-contiguous NT stores.
// ---------------------------------------------------------------------------
#define LDS_TOTAL 36864
// map: A [0,16384); B [16384,32768); epi stage [0,32768) alias;
//      colpart [32768,+2048); invn [34816,+512); ctm [35328,+512);
//      ftl [35840,+512); lab [36352,+512)

__global__ __launch_bounds__(512, 6) void gemm_kernel(
    const float* __restrict__ Kg, const unsigned char* __restrict__ wsA,
    const float* __restrict__ ctm_g, const float* __restrict__ ftl_g,
    const int* __restrict__ label, const float* __restrict__ tnew_g,
    float* __restrict__ out1, float* __restrict__ out2)
{
  __shared__ __align__(16) unsigned char smem[LDS_TOTAL];

  int t = threadIdx.x;
  int lane = t & 63, wv = t >> 6;
  int wm = wv >> 2, wn = wv & 3;  // 2M x 4N
  int kq = lane >> 4, lr = lane & 15;

  // XCD swizzle: nwg=3128=8*391 -> swz = xcd*391 + seq (bijective).
  // Logical bid = pid*4 + mq: a pid's 4 m-blocks contiguous on one XCD
  // -> B panel fetched once into that L2, 4x reuse.
  int bid = blockIdx.x;
  {
    int xcd = bid & 7, seq = bid >> 3;
    bid = xcd * 391 + seq;
  }
  int pid = bid >> 2, mq = bid & 3;
  long c0 = (long)pid * 128;

  // B staging: thread owns column c (t&127), k-segment kseg (t>>7): 16 k's
  int c = t & 127, kseg = t >> 7;
  bool binb = (c0 + c) < C_N;
  const float* Bcol = Kg + c0 + c + (size_t)kseg * 16 * C_N;

  f32x4 acc[4][2] = {};
  float csq = 0.f;
  float bf[16];

  const unsigned char* wsTile = wsA + (size_t)mq * (8 * 16384);
  unsigned char* smemA = smem;
  unsigned char* smemB = smem + 16384;
  unsigned char* browB = smemB + c * 128;

#define LOAD_B(j)                                                            \
  {                                                                          \
    const float* src = Bcol + (size_t)((j) * 64) * C_N;                      \
    _Pragma("unroll") for (int i = 0; i < 16; ++i)                           \
        bf[i] = binb ? src[(size_t)i * C_N] : 0.f;                           \
  }

#define WRITE_B()                                                            \
  {                                                                          \
    _Pragma("unroll") for (int i = 0; i < 16; ++i) csq += bf[i] * bf[i];     \
    union { unsigned short u[16]; uint4 q[2]; } pk;                          \
    _Pragma("unroll") for (int i = 0; i < 16; ++i) pk.u[i] = f2bf(bf[i]);    \
    _Pragma("unroll") for (int h = 0; h < 2; ++h)                            \
      *(uint4*)(browB + ((kseg * 32 + h * 16) ^ ((c & 7) << 4))) = pk.q[h];  \
  }

  LOAD_B(0);

  // ---- main loop: 8 K-steps. A staged per-step (single buffer), B 1-ahead.
#pragma unroll
  for (int kkt = 0; kkt < 8; ++kkt) {
    __syncthreads();  // BARRIER-A: prior compute's LDS reads complete
    // stage A[kkt]: 2 gll per thread (issued before WRITE_B's B-wait)
    const unsigned char* tA = wsTile + (size_t)kkt * 16384;
#pragma unroll
    for (int i = 0; i < 2; ++i) {
      int off = wv * 2048 + i * 1024;
      __builtin_amdgcn_global_load_lds((gptr_t)(tA + off + lane * 16),
                                       (sptr_t)(smemA + off), 16, 0, 0);
    }
    __builtin_amdgcn_sched_barrier(0);
    WRITE_B();  // B[kkt] regs -> LDS (compiler waits those, keeps A glls)
    if (kkt < 7) LOAD_B(kkt + 1);  // 16 loads stay in flight across barrier
    __builtin_amdgcn_sched_barrier(0);
    // retire the 2 A-DMAs (oldest); keep B[kkt+1] (16 newest) outstanding
    if (kkt < 7) {
      asm volatile("s_waitcnt vmcnt(16)" ::: "memory");
    } else {
      asm volatile("s_waitcnt vmcnt(0)" ::: "memory");
    }
    __builtin_amdgcn_sched_barrier(0);
    __syncthreads();  // BARRIER-B: A[kkt] landed, B[kkt] visible

#pragma unroll
    for (int ks = 0; ks < 2; ++ks) {
      int kb = ks * 64 + kq * 16;
      bf16x8 bfr[2];
#pragma unroll
      for (int nf = 0; nf < 2; ++nf) {
        int n = wn * 32 + nf * 16 + lr;
        bfr[nf] = *(const bf16x8*)(smemB + n * 128 + (kb ^ ((n & 7) << 4)));
      }
#pragma unroll
      for (int mf = 0; mf < 4; ++mf) {
        int m = wm * 64 + mf * 16 + lr;
        bf16x8 afr = *(const bf16x8*)(smemA + m * 128 + (kb ^ ((m & 7) << 4)));
        acc[mf][0] = __builtin_amdgcn_mfma_f32_16x16x32_bf16(afr, bfr[0], acc[mf][0], 0, 0, 0);
        acc[mf][1] = __builtin_amdgcn_mfma_f32_16x16x32_bf16(afr, bfr[1], acc[mf][1], 0, 0, 0);
      }
    }
  }

  // ---- column norms + per-row params
  float* colpart = (float*)(smem + 32768);  // [512]
  float* invn    = (float*)(smem + 34816);  // [128]
  float* ctm_s   = (float*)(smem + 35328);  // [128]
  float* ftl_s   = (float*)(smem + 35840);  // [128]
  int*   lab_s   = (int*)  (smem + 36352);  // [128]
  colpart[t] = csq;
  if (t < 128) {
    ctm_s[t] = ctm_g[mq * 128 + t];
    ftl_s[t] = ftl_g[mq * 128 + t];
    lab_s[t] = label[mq * 128 + t];
  }
  __syncthreads();
  if (t < 128) {
    float s = colpart[t] + colpart[t + 128] + colpart[t + 256] + colpart[t + 384];
    invn[t] = 1.0f / sqrtf(fmaxf(s, 1e-30f));
  }
  __syncthreads();
  float tn = tnew_g[0];

  // ---- epilogue: 2 chunks of 64 rows; stage acc in LDS (aliases A+B,
  // two barriers since last LDS read), stream 512B-contiguous rows, NT.
  for (int q = 0; q < 2; ++q) {
    if (wm == q) {
#pragma unroll
      for (int mf = 0; mf < 4; ++mf) {
#pragma unroll
        for (int nf = 0; nf < 2; ++nf) {
#pragma unroll
          for (int j = 0; j < 4; ++j) {
            int row = mf * 16 + kq * 4 + j;   // [0,64)
            int col = wn * 32 + nf * 16 + lr; // [0,128)
            *(float*)(smem + row * 512 + ((col * 4) ^ (((row >> 2) & 3) << 6))) =
                acc[mf][nf][j];
          }
        }
      }
    }
    __syncthreads();
#pragma unroll
    for (int rr = 0; rr < 4; ++rr) {
      int row = rr * 16 + (t >> 5);   // [0,64)
      int cb = (t & 31) * 4;          // col base [0,128)
      f32x4 v = *(const f32x4*)(smem + row * 512 + ((cb * 4) ^ (((row >> 2) & 3) << 6)));
      long cgs = c0 + cb;
      if (cgs < C_N) {  // group fully valid (C_N % 4 == 0)
        int lrow = q * 64 + row;
        float cm = ctm_s[lrow], fl = ftl_s[lrow];
        int lb = lab_s[lrow];
        f32x4 iv = *(const f32x4*)(invn + cb);
        f32x4 o1v, o2v;
#pragma unroll
        for (int jj = 0; jj < 4; ++jj) {
          float cosv = fminf(1.f, fmaxf(-1.f, v[jj] * iv[jj]));
          o2v[jj] = cosv * S_SCALE;
          float ct = (cosv > cm) ? cosv * (tn + cosv) : cosv;
          if (lb == (int)(cgs + jj)) ct = fl;
          o1v[jj] = ct * S_SCALE;
        }
        size_t idx = (size_t)(mq * 128 + lrow) * C_N + cgs;
        __builtin_nontemporal_store(o1v, (f32x4*)(out1 + idx));
        __builtin_nontemporal_store(o2v, (f32x4*)(out2 + idx));
      }
    }
    __syncthreads();
  }
#undef LOAD_B
#undef WRITE_B
}

// ---------------------------------------------------------------------------
extern "C" void kernel_launch(void* const* d_in, const int* in_sizes, int n_in,
                              void* d_out, int out_size, void* d_ws, size_t ws_size,
                              hipStream_t stream)
{
  const float* emb   = (const float*)d_in[0];
  const float* Kg    = (const float*)d_in[1];
  const float* t_in  = (const float*)d_in[2];
  const int*   label = (const int*)d_in[3];

  float* out1 = (float*)d_out;                 // output * S   [512*100000]
  float* out2 = out1 + (size_t)B_M * C_N;      // origin * S   [512*100000]
  float* out3 = out1 + 2 * (size_t)B_M * C_N;  // scalar loss

  unsigned char* wsA = (unsigned char*)d_ws;   // 512KB swizzled bf16 A tiles
  float* tl   = (float*)((unsigned char*)d_ws + 524288);
  float* ctm  = tl + 512;
  float* ftl  = ctm + 512;
  float* tnew = ftl + 512;

  prep_kernel<<<512, 256, 0, stream>>>(emb, Kg, label, wsA, tl);
  finalize_kernel<<<1, 512, 0, stream>>>(tl, t_in, ctm, ftl, tnew, out3);
  int nb = 4 * 782;  // BN=128 -> 782 pids x 4 mq = 3128
  gemm_kernel<<<nb, 512, 0, stream>>>(Kg, wsA, ctm, ftl, label, tnew, out1, out2);
}

// Round 9
// 375.411 us; speedup vs baseline: 1.7446x; 1.7446x over previous
//
#include <hip/hip_runtime.h>
#include <hip/hip_bf16.h>
#include <stdint.h>

// Problem constants
#define B_M 512
#define D_K 512
#define C_N 100000
#define S_SCALE 64.0f
#define W_LOSS 0.003f
#define COS_M_C 0.79608379854905604f
#define SIN_M_C 0.60518640573603957f
#define THRESH_C (-0.79608379854905604f)
#define MM_C 0.39337116372842573f

typedef __bf16 bf16x8 __attribute__((ext_vector_type(8)));
typedef float f32x4 __attribute__((ext_vector_type(4)));

typedef const __attribute__((address_space(1))) unsigned char* gptr_t;
typedef __attribute__((address_space(3))) unsigned char* sptr_t;

__device__ __forceinline__ unsigned short f2bf(float f) {
  __bf16 h = (__bf16)f;
  return __builtin_bit_cast(unsigned short, h);
}

// ---------------------------------------------------------------------------
// Kernel 1: normalize emb rows (f32), write swizzled bf16 A-tiles to ws,
// compute target_logit[b] exactly in f32.
// wsA layout: 32 tiles (mq 0..3  x  ktile 0..7) of 16 KB;
// tile = [128 rows][128 B], byte-in-row XOR ((row&7)<<4)  (LDS image).
// ---------------------------------------------------------------------------
__global__ __launch_bounds__(256) void prep_kernel(
    const float* __restrict__ emb, const float* __restrict__ Kg,
    const int* __restrict__ label, unsigned char* __restrict__ wsA,
    float* __restrict__ tl)
{
  int b = blockIdx.x, t = threadIdx.x;
  __shared__ float row[512];
  __shared__ float r1[256], r2[256];

  float2 v = ((const float2*)(emb + (size_t)b * 512))[t];
  r1[t] = v.x * v.x + v.y * v.y;
  __syncthreads();
  for (int s = 128; s > 0; s >>= 1) {
    if (t < s) r1[t] += r1[t + s];
    __syncthreads();
  }
  float inv = 1.0f / sqrtf(r1[0]);
  float e0 = v.x * inv, e1 = v.y * inv;
  row[2 * t] = e0;
  row[2 * t + 1] = e1;

  {
    int mq = b >> 7, lrow = b & 127;
    int kk = t >> 5;  // (2t)/64 : k-tile index
    int byte_in = (4 * (t & 31)) ^ ((lrow & 7) << 4);
    ushort2 h;
    h.x = f2bf(e0);
    h.y = f2bf(e1);
    *(ushort2*)(wsA + (size_t)(mq * 8 + kk) * 16384 + lrow * 128 + byte_in) = h;
  }
  __syncthreads();

  int lab = label[b];
  const float* kc = Kg + lab;
  float dot = 0.f, csq = 0.f;
  for (int d = t; d < 512; d += 256) {
    float kv = kc[(size_t)d * C_N];
    dot += row[d] * kv;
    csq += kv * kv;
  }
  r1[t] = dot;
  r2[t] = csq;
  __syncthreads();
  for (int s = 128; s > 0; s >>= 1) {
    if (t < s) { r1[t] += r1[t + s]; r2[t] += r2[t + s]; }
    __syncthreads();
  }
  if (t == 0) {
    float tlv = r1[0] / sqrtf(r2[0]);
    tl[b] = fminf(1.f, fmaxf(-1.f, tlv));
  }
}

// ---------------------------------------------------------------------------
// Kernel 2: t_new, cos_theta_m[b], final_target_logit[b], center-loss scalar.
// ---------------------------------------------------------------------------
__global__ __launch_bounds__(512) void finalize_kernel(
    const float* __restrict__ tl, const float* __restrict__ t_in,
    float* __restrict__ ctm, float* __restrict__ ftl,
    float* __restrict__ tnew, float* __restrict__ out3)
{
  int t = threadIdx.x;
  float v = tl[t];
  __shared__ float r1[512], r2[512];
  float ac = acosf(v);
  r1[t] = v;
  r2[t] = ac * sqrtf(ac);  // acos^1.5
  __syncthreads();
  for (int s = 256; s > 0; s >>= 1) {
    if (t < s) { r1[t] += r1[t + s]; r2[t] += r2[t + s]; }
    __syncthreads();
  }
  if (t == 0) {
    tnew[0] = 0.99f * t_in[0] + 0.01f * (r1[0] / 512.0f);
    out3[0] = S_SCALE * W_LOSS * (r2[0] / 512.0f);
  }
  float st = sqrtf(fmaxf(0.f, 1.f - v * v));
  float cm = v * COS_M_C - st * SIN_M_C;
  ctm[t] = cm;
  ftl[t] = (v > THRESH_C) ? cm : (v - MM_C);
}

// ---------------------------------------------------------------------------
// Kernel 3: fused GEMM + epilogue. R7's sync skeleton, R8's geometry,
// NO aggressive launch-bounds clamp (R6/R8 lesson: (512,6) -> spill disaster).
// BM=128, BN=128, BK=64; 512 threads, 8 waves (2M x 4N), wave tile 64x32.
// A single-buffer LDS (16KB) staged per step via 2 gll/thread (L2-resident
// ws). B single 16KB buffer, float2-per-lane staging (wave = 512B
// contiguous reads), 1-step register prefetch; counted vmcnt(8) retires the
// 2 A-DMAs, keeps B[k+1]'s 8 loads in flight across the barrier.
// Epilogue: acc -> LDS (f32, XOR-swizzled) -> 512B-contiguous NT stores.
// ---------------------------------------------------------------------------
#define LDS_TOTAL 38912
// map: A [0,16384); B [16384,32768); epi stage [0,32768) alias;
//      colpart [32768,+4096); invn [36864,+512); ctm [37376,+512);
//      ftl [37888,+512); lab [38400,+512)

__global__ __launch_bounds__(512, 4) void gemm_kernel(
    const float* __restrict__ Kg, const unsigned char* __restrict__ wsA,
    const float* __restrict__ ctm_g, const float* __restrict__ ftl_g,
    const int* __restrict__ label, const float* __restrict__ tnew_g,
    float* __restrict__ out1, float* __restrict__ out2)
{
  __shared__ __align__(16) unsigned char smem[LDS_TOTAL];

  int t = threadIdx.x;
  int lane = t & 63, wv = t >> 6;
  int wm = wv >> 2, wn = wv & 3;  // 2M x 4N
  int kq = lane >> 4, lr = lane & 15;

  // XCD swizzle: nwg=3128=8*391 -> swz = xcd*391 + seq (bijective).
  // Logical bid = pid*4 + mq: a pid's 4 m-blocks contiguous on one XCD
  // -> B panel fetched once into that L2, 4x reuse.
  int bid = blockIdx.x;
  {
    int xcd = bid & 7, seq = bid >> 3;
    bid = xcd * 391 + seq;
  }
  int pid = bid >> 2, mq = bid & 3;
  long c0 = (long)pid * 128;

  // B staging: thread owns cols {cola, cola+1} (float2), kseg (t>>6): 8 rows.
  // C_N even + cola even -> both cols valid or both invalid together.
  int cola = (t & 63) * 2, kseg = t >> 6;
  bool binb = (c0 + cola) < C_N;
  const float* Bsrc = Kg + c0 + cola + (size_t)kseg * 8 * C_N;
  const float2 zero2 = {0.f, 0.f};

  f32x4 acc[4][2] = {};
  float csqa = 0.f, csqb = 0.f;
  float2 bf[8];

  const unsigned char* wsTile = wsA + (size_t)mq * (8 * 16384);
  unsigned char* smemA = smem;
  unsigned char* smemB = smem + 16384;
  unsigned char* browA = smemB + cola * 128;
  unsigned char* browB = smemB + (cola + 1) * 128;

#define LOAD_B(j)                                                            \
  {                                                                          \
    const float* src = Bsrc + (size_t)((j) * 64) * C_N;                      \
    _Pragma("unroll") for (int i = 0; i < 8; ++i)                            \
        bf[i] = binb ? *(const float2*)(src + (size_t)i * C_N) : zero2;      \
  }

#define WRITE_B()                                                            \
  {                                                                          \
    union { unsigned short u[8]; uint4 q; } pa, pb;                          \
    _Pragma("unroll") for (int i = 0; i < 8; ++i) {                          \
      csqa += bf[i].x * bf[i].x;                                             \
      csqb += bf[i].y * bf[i].y;                                             \
      pa.u[i] = f2bf(bf[i].x);                                               \
      pb.u[i] = f2bf(bf[i].y);                                               \
    }                                                                        \
    *(uint4*)(browA + ((kseg * 16) ^ ((cola & 7) << 4))) = pa.q;             \
    *(uint4*)(browB + ((kseg * 16) ^ (((cola + 1) & 7) << 4))) = pb.q;       \
  }

  LOAD_B(0);

  // ---- main loop: 8 K-steps. A staged per-step (single buffer), B 1-ahead.
#pragma unroll
  for (int kkt = 0; kkt < 8; ++kkt) {
    __syncthreads();  // BARRIER-A: prior compute's LDS reads complete
    // stage A[kkt]: 2 gll per thread (issued before WRITE_B's B-wait)
    const unsigned char* tA = wsTile + (size_t)kkt * 16384;
#pragma unroll
    for (int i = 0; i < 2; ++i) {
      int off = wv * 2048 + i * 1024;
      __builtin_amdgcn_global_load_lds((gptr_t)(tA + off + lane * 16),
                                       (sptr_t)(smemA + off), 16, 0, 0);
    }
    __builtin_amdgcn_sched_barrier(0);
    WRITE_B();  // B[kkt] regs -> LDS (compiler waits those, keeps A glls)
    if (kkt < 7) LOAD_B(kkt + 1);  // 8 loads stay in flight across barrier
    __builtin_amdgcn_sched_barrier(0);
    // retire the 2 A-DMAs (oldest); keep B[kkt+1] (8 newest) outstanding
    if (kkt < 7) {
      asm volatile("s_waitcnt vmcnt(8)" ::: "memory");
    } else {
      asm volatile("s_waitcnt vmcnt(0)" ::: "memory");
    }
    __builtin_amdgcn_sched_barrier(0);
    __syncthreads();  // BARRIER-B: A[kkt] landed, B[kkt] visible

#pragma unroll
    for (int ks = 0; ks < 2; ++ks) {
      int kb = ks * 64 + kq * 16;
      bf16x8 bfr[2];
#pragma unroll
      for (int nf = 0; nf < 2; ++nf) {
        int n = wn * 32 + nf * 16 + lr;
        bfr[nf] = *(const bf16x8*)(smemB + n * 128 + (kb ^ ((n & 7) << 4)));
      }
#pragma unroll
      for (int mf = 0; mf < 4; ++mf) {
        int m = wm * 64 + mf * 16 + lr;
        bf16x8 afr = *(const bf16x8*)(smemA + m * 128 + (kb ^ ((m & 7) << 4)));
        acc[mf][0] = __builtin_amdgcn_mfma_f32_16x16x32_bf16(afr, bfr[0], acc[mf][0], 0, 0, 0);
        acc[mf][1] = __builtin_amdgcn_mfma_f32_16x16x32_bf16(afr, bfr[1], acc[mf][1], 0, 0, 0);
      }
    }
  }

  // ---- column norms + per-row params
  float* colpart = (float*)(smem + 32768);  // [8][128]
  float* invn    = (float*)(smem + 36864);  // [128]
  float* ctm_s   = (float*)(smem + 37376);  // [128]
  float* ftl_s   = (float*)(smem + 37888);  // [128]
  int*   lab_s   = (int*)  (smem + 38400);  // [128]
  colpart[kseg * 128 + cola] = csqa;
  colpart[kseg * 128 + cola + 1] = csqb;
  if (t < 128) {
    ctm_s[t] = ctm_g[mq * 128 + t];
    ftl_s[t] = ftl_g[mq * 128 + t];
    lab_s[t] = label[mq * 128 + t];
  }
  __syncthreads();
  if (t < 128) {
    float s = 0.f;
#pragma unroll
    for (int g = 0; g < 8; ++g) s += colpart[g * 128 + t];
    invn[t] = 1.0f / sqrtf(fmaxf(s, 1e-30f));
  }
  __syncthreads();
  float tn = tnew_g[0];

  // ---- epilogue: 2 chunks of 64 rows; stage acc in LDS (aliases A+B,
  // two barriers since last LDS read), stream 512B-contiguous rows, NT.
  for (int q = 0; q < 2; ++q) {
    if (wm == q) {
#pragma unroll
      for (int mf = 0; mf < 4; ++mf) {
#pragma unroll
        for (int nf = 0; nf < 2; ++nf) {
#pragma unroll
          for (int j = 0; j < 4; ++j) {
            int row = mf * 16 + kq * 4 + j;   // [0,64)
            int col = wn * 32 + nf * 16 + lr; // [0,128)
            *(float*)(smem + row * 512 + ((col * 4) ^ (((row >> 2) & 3) << 6))) =
                acc[mf][nf][j];
          }
        }
      }
    }
    __syncthreads();
#pragma unroll
    for (int rr = 0; rr < 4; ++rr) {
      int row = rr * 16 + (t >> 5);   // [0,64)
      int cb = (t & 31) * 4;          // col base [0,128)
      f32x4 v = *(const f32x4*)(smem + row * 512 + ((cb * 4) ^ (((row >> 2) & 3) << 6)));
      long cgs = c0 + cb;
      if (cgs < C_N) {  // group fully valid (C_N % 4 == 0)
        int lrow = q * 64 + row;
        float cm = ctm_s[lrow], fl = ftl_s[lrow];
        int lb = lab_s[lrow];
        f32x4 iv = *(const f32x4*)(invn + cb);
        f32x4 o1v, o2v;
#pragma unroll
        for (int jj = 0; jj < 4; ++jj) {
          float cosv = fminf(1.f, fmaxf(-1.f, v[jj] * iv[jj]));
          o2v[jj] = cosv * S_SCALE;
          float ct = (cosv > cm) ? cosv * (tn + cosv) : cosv;
          if (lb == (int)(cgs + jj)) ct = fl;
          o1v[jj] = ct * S_SCALE;
        }
        size_t idx = (size_t)(mq * 128 + lrow) * C_N + cgs;
        __builtin_nontemporal_store(o1v, (f32x4*)(out1 + idx));
        __builtin_nontemporal_store(o2v, (f32x4*)(out2 + idx));
      }
    }
    __syncthreads();
  }
#undef LOAD_B
#undef WRITE_B
}

// ---------------------------------------------------------------------------
extern "C" void kernel_launch(void* const* d_in, const int* in_sizes, int n_in,
                              void* d_out, int out_size, void* d_ws, size_t ws_size,
                              hipStream_t stream)
{
  const float* emb   = (const float*)d_in[0];
  const float* Kg    = (const float*)d_in[1];
  const float* t_in  = (const float*)d_in[2];
  const int*   label = (const int*)d_in[3];

  float* out1 = (float*)d_out;                 // output * S   [512*100000]
  float* out2 = out1 + (size_t)B_M * C_N;      // origin * S   [512*100000]
  float* out3 = out1 + 2 * (size_t)B_M * C_N;  // scalar loss

  unsigned char* wsA = (unsigned char*)d_ws;   // 512KB swizzled bf16 A tiles
  float* tl   = (float*)((unsigned char*)d_ws + 524288);
  float* ctm  = tl + 512;
  float* ftl  = ctm + 512;
  float* tnew = ftl + 512;

  prep_kernel<<<512, 256, 0, stream>>>(emb, Kg, label, wsA, tl);
  finalize_kernel<<<1, 512, 0, stream>>>(tl, t_in, ctm, ftl, tnew, out3);
  int nb = 4 * 782;  // BN=128 -> 782 pids x 4 mq = 3128
  gemm_kernel<<<nb, 512, 0, stream>>>(Kg, wsA, ctm, ftl, label, tnew, out1, out2);
}

// Round 10
// 188.308 us; speedup vs baseline: 3.4779x; 1.9936x over previous
//
#include <hip/hip_runtime.h>
#include <hip/hip_bf16.h>
#include <stdint.h>

// Problem constants
#define B_M 512
#define D_K 512
#define C_N 100000
#define S_SCALE 64.0f
#define W_LOSS 0.003f
#define COS_M_C 0.79608379854905604f
#define SIN_M_C 0.60518640573603957f
#define THRESH_C (-0.79608379854905604f)
#define MM_C 0.39337116372842573f

typedef __bf16 bf16x8 __attribute__((ext_vector_type(8)));
typedef float f32x4 __attribute__((ext_vector_type(4)));

typedef const __attribute__((address_space(1))) unsigned char* gptr_t;
typedef __attribute__((address_space(3))) unsigned char* sptr_t;

__device__ __forceinline__ unsigned short f2bf(float f) {
  __bf16 h = (__bf16)f;
  return __builtin_bit_cast(unsigned short, h);
}

// ---------------------------------------------------------------------------
// Kernel 1: normalize emb rows (f32), write swizzled bf16 A-tiles to ws,
// compute target_logit[b] exactly in f32.
// wsA layout: 32 tiles (mq 0..3  x  ktile 0..7) of 16 KB;
// tile = [128 rows][128 B], byte-in-row XOR ((row&7)<<4)  (LDS image).
// ---------------------------------------------------------------------------
__global__ __launch_bounds__(256) void prep_kernel(
    const float* __restrict__ emb, const float* __restrict__ Kg,
    const int* __restrict__ label, unsigned char* __restrict__ wsA,
    float* __restrict__ tl)
{
  int b = blockIdx.x, t = threadIdx.x;
  __shared__ float row[512];
  __shared__ float r1[256], r2[256];

  float2 v = ((const float2*)(emb + (size_t)b * 512))[t];
  r1[t] = v.x * v.x + v.y * v.y;
  __syncthreads();
  for (int s = 128; s > 0; s >>= 1) {
    if (t < s) r1[t] += r1[t + s];
    __syncthreads();
  }
  float inv = 1.0f / sqrtf(r1[0]);
  float e0 = v.x * inv, e1 = v.y * inv;
  row[2 * t] = e0;
  row[2 * t + 1] = e1;

  {
    int mq = b >> 7, lrow = b & 127;
    int kk = t >> 5;  // (2t)/64 : k-tile index
    int byte_in = (4 * (t & 31)) ^ ((lrow & 7) << 4);
    ushort2 h;
    h.x = f2bf(e0);
    h.y = f2bf(e1);
    *(ushort2*)(wsA + (size_t)(mq * 8 + kk) * 16384 + lrow * 128 + byte_in) = h;
  }
  __syncthreads();

  int lab = label[b];
  const float* kc = Kg + lab;
  float dot = 0.f, csq = 0.f;
  for (int d = t; d < 512; d += 256) {
    float kv = kc[(size_t)d * C_N];
    dot += row[d] * kv;
    csq += kv * kv;
  }
  r1[t] = dot;
  r2[t] = csq;
  __syncthreads();
  for (int s = 128; s > 0; s >>= 1) {
    if (t < s) { r1[t] += r1[t + s]; r2[t] += r2[t + s]; }
    __syncthreads();
  }
  if (t == 0) {
    float tlv = r1[0] / sqrtf(r2[0]);
    tl[b] = fminf(1.f, fmaxf(-1.f, tlv));
  }
}

// ---------------------------------------------------------------------------
// Kernel 2: t_new, cos_theta_m[b], final_target_logit[b], center-loss scalar.
// ---------------------------------------------------------------------------
__global__ __launch_bounds__(512) void finalize_kernel(
    const float* __restrict__ tl, const float* __restrict__ t_in,
    float* __restrict__ ctm, float* __restrict__ ftl,
    float* __restrict__ tnew, float* __restrict__ out3)
{
  int t = threadIdx.x;
  float v = tl[t];
  __shared__ float r1[512], r2[512];
  float ac = acosf(v);
  r1[t] = v;
  r2[t] = ac * sqrtf(ac);  // acos^1.5
  __syncthreads();
  for (int s = 256; s > 0; s >>= 1) {
    if (t < s) { r1[t] += r1[t + s]; r2[t] += r2[t + s]; }
    __syncthreads();
  }
  if (t == 0) {
    tnew[0] = 0.99f * t_in[0] + 0.01f * (r1[0] / 512.0f);
    out3[0] = S_SCALE * W_LOSS * (r2[0] / 512.0f);
  }
  float st = sqrtf(fmaxf(0.f, 1.f - v * v));
  float cm = v * COS_M_C - st * SIN_M_C;
  ctm[t] = cm;
  ftl[t] = (v > THRESH_C) ? cm : (v - MM_C);
}

// ---------------------------------------------------------------------------
// Kernel 3: fused GEMM + epilogue. R8 geometry with the spill poison removed:
// __launch_bounds__(512,2) -> 256-reg tier, allocator never spills (R6/R8/R9
// lesson: hinting below the organic ~100-reg need makes the allocator clamp
// to a 40/64-reg tier and bleed scratch traffic -> FETCH/WRITE inflate 2x).
// BM=128, BN=128, BK=64; 512 threads, 8 waves (2M x 4N), wave tile 64x32.
// A single-buffer LDS (16KB), staged per step via 2 gll/thread from the
// L2-resident ws image. B single 16KB buffer, scalar-column staging
// (c=t&127: all 8 XOR groups -> 2-way-free ds_write, measured 0 conflicts);
// counted vmcnt(16) retires the 2 A-DMAs, keeps B[k+1] in flight.
// Epilogue: acc -> LDS (f32, XOR-swizzled) -> 512B-contiguous NT stores.
// ---------------------------------------------------------------------------
#define LDS_TOTAL 36864
// map: A [0,16384); B [16384,32768); epi stage [0,32768) alias;
//      colpart [32768,+2048); invn [34816,+512); ctm [35328,+512);
//      ftl [35840,+512); lab [36352,+512)

__global__ __launch_bounds__(512, 2) void gemm_kernel(
    const float* __restrict__ Kg, const unsigned char* __restrict__ wsA,
    const float* __restrict__ ctm_g, const float* __restrict__ ftl_g,
    const int* __restrict__ label, const float* __restrict__ tnew_g,
    float* __restrict__ out1, float* __restrict__ out2)
{
  __shared__ __align__(16) unsigned char smem[LDS_TOTAL];

  int t = threadIdx.x;
  int lane = t & 63, wv = t >> 6;
  int wm = wv >> 2, wn = wv & 3;  // 2M x 4N
  int kq = lane >> 4, lr = lane & 15;

  // XCD swizzle: nwg=3128=8*391 -> swz = xcd*391 + seq (bijective).
  // Logical bid = pid*4 + mq: a pid's 4 m-blocks contiguous on one XCD
  // -> B panel fetched once into that L2, 4x reuse.
  int bid = blockIdx.x;
  {
    int xcd = bid & 7, seq = bid >> 3;
    bid = xcd * 391 + seq;
  }
  int pid = bid >> 2, mq = bid & 3;
  long c0 = (long)pid * 128;

  // B staging: thread owns column c (t&127), k-segment kseg (t>>7): 16 k's
  int c = t & 127, kseg = t >> 7;
  bool binb = (c0 + c) < C_N;
  const float* Bcol = Kg + c0 + c + (size_t)kseg * 16 * C_N;

  f32x4 acc[4][2] = {};
  float csq = 0.f;
  float bf[16];

  const unsigned char* wsTile = wsA + (size_t)mq * (8 * 16384);
  unsigned char* smemA = smem;
  unsigned char* smemB = smem + 16384;
  unsigned char* browB = smemB + c * 128;

#define LOAD_B(j)                                                            \
  {                                                                          \
    const float* src = Bcol + (size_t)((j) * 64) * C_N;                      \
    _Pragma("unroll") for (int i = 0; i < 16; ++i)                           \
        bf[i] = binb ? src[(size_t)i * C_N] : 0.f;                           \
  }

#define WRITE_B()                                                            \
  {                                                                          \
    _Pragma("unroll") for (int i = 0; i < 16; ++i) csq += bf[i] * bf[i];     \
    union { unsigned short u[16]; uint4 q[2]; } pk;                          \
    _Pragma("unroll") for (int i = 0; i < 16; ++i) pk.u[i] = f2bf(bf[i]);    \
    _Pragma("unroll") for (int h = 0; h < 2; ++h)                            \
      *(uint4*)(browB + ((kseg * 32 + h * 16) ^ ((c & 7) << 4))) = pk.q[h];  \
  }

  LOAD_B(0);

  // ---- main loop: 8 K-steps. A staged per-step (single buffer), B 1-ahead.
#pragma unroll
  for (int kkt = 0; kkt < 8; ++kkt) {
    __syncthreads();  // BARRIER-A: prior compute's LDS reads complete
    // stage A[kkt]: 2 gll per thread (issued before WRITE_B's B-wait)
    const unsigned char* tA = wsTile + (size_t)kkt * 16384;
#pragma unroll
    for (int i = 0; i < 2; ++i) {
      int off = wv * 2048 + i * 1024;
      __builtin_amdgcn_global_load_lds((gptr_t)(tA + off + lane * 16),
                                       (sptr_t)(smemA + off), 16, 0, 0);
    }
    __builtin_amdgcn_sched_barrier(0);
    WRITE_B();  // B[kkt] regs -> LDS (compiler waits those, keeps A glls)
    if (kkt < 7) LOAD_B(kkt + 1);  // 16 loads stay in flight across barrier
    __builtin_amdgcn_sched_barrier(0);
    // retire the 2 A-DMAs (oldest); keep B[kkt+1] (16 newest) outstanding
    if (kkt < 7) {
      asm volatile("s_waitcnt vmcnt(16)" ::: "memory");
    } else {
      asm volatile("s_waitcnt vmcnt(0)" ::: "memory");
    }
    __builtin_amdgcn_sched_barrier(0);
    __syncthreads();  // BARRIER-B: A[kkt] landed, B[kkt] visible

#pragma unroll
    for (int ks = 0; ks < 2; ++ks) {
      int kb = ks * 64 + kq * 16;
      bf16x8 bfr[2];
#pragma unroll
      for (int nf = 0; nf < 2; ++nf) {
        int n = wn * 32 + nf * 16 + lr;
        bfr[nf] = *(const bf16x8*)(smemB + n * 128 + (kb ^ ((n & 7) << 4)));
      }
#pragma unroll
      for (int mf = 0; mf < 4; ++mf) {
        int m = wm * 64 + mf * 16 + lr;
        bf16x8 afr = *(const bf16x8*)(smemA + m * 128 + (kb ^ ((m & 7) << 4)));
        acc[mf][0] = __builtin_amdgcn_mfma_f32_16x16x32_bf16(afr, bfr[0], acc[mf][0], 0, 0, 0);
        acc[mf][1] = __builtin_amdgcn_mfma_f32_16x16x32_bf16(afr, bfr[1], acc[mf][1], 0, 0, 0);
      }
    }
  }

  // ---- column norms + per-row params
  float* colpart = (float*)(smem + 32768);  // [4][128]
  float* invn    = (float*)(smem + 34816);  // [128]
  float* ctm_s   = (float*)(smem + 35328);  // [128]
  float* ftl_s   = (float*)(smem + 35840);  // [128]
  int*   lab_s   = (int*)  (smem + 36352);  // [128]
  colpart[t] = csq;
  if (t < 128) {
    ctm_s[t] = ctm_g[mq * 128 + t];
    ftl_s[t] = ftl_g[mq * 128 + t];
    lab_s[t] = label[mq * 128 + t];
  }
  __syncthreads();
  if (t < 128) {
    float s = colpart[t] + colpart[t + 128] + colpart[t + 256] + colpart[t + 384];
    invn[t] = 1.0f / sqrtf(fmaxf(s, 1e-30f));
  }
  __syncthreads();
  float tn = tnew_g[0];

  // ---- epilogue: 2 chunks of 64 rows; stage acc in LDS (aliases A+B,
  // two barriers since last LDS read), stream 512B-contiguous rows, NT.
  for (int q = 0; q < 2; ++q) {
    if (wm == q) {
#pragma unroll
      for (int mf = 0; mf < 4; ++mf) {
#pragma unroll
        for (int nf = 0; nf < 2; ++nf) {
#pragma unroll
          for (int j = 0; j < 4; ++j) {
            int row = mf * 16 + kq * 4 + j;   // [0,64)
            int col = wn * 32 + nf * 16 + lr; // [0,128)
            *(float*)(smem + row * 512 + ((col * 4) ^ (((row >> 2) & 3) << 6))) =
                acc[mf][nf][j];
          }
        }
      }
    }
    __syncthreads();
#pragma unroll
    for (int rr = 0; rr < 4; ++rr) {
      int row = rr * 16 + (t >> 5);   // [0,64)
      int cb = (t & 31) * 4;          // col base [0,128)
      f32x4 v = *(const f32x4*)(smem + row * 512 + ((cb * 4) ^ (((row >> 2) & 3) << 6)));
      long cgs = c0 + cb;
      if (cgs < C_N) {  // group fully valid (C_N % 4 == 0)
        int lrow = q * 64 + row;
        float cm = ctm_s[lrow], fl = ftl_s[lrow];
        int lb = lab_s[lrow];
        f32x4 iv = *(const f32x4*)(invn + cb);
        f32x4 o1v, o2v;
#pragma unroll
        for (int jj = 0; jj < 4; ++jj) {
          float cosv = fminf(1.f, fmaxf(-1.f, v[jj] * iv[jj]));
          o2v[jj] = cosv * S_SCALE;
          float ct = (cosv > cm) ? cosv * (tn + cosv) : cosv;
          if (lb == (int)(cgs + jj)) ct = fl;
          o1v[jj] = ct * S_SCALE;
        }
        size_t idx = (size_t)(mq * 128 + lrow) * C_N + cgs;
        __builtin_nontemporal_store(o1v, (f32x4*)(out1 + idx));
        __builtin_nontemporal_store(o2v, (f32x4*)(out2 + idx));
      }
    }
    __syncthreads();
  }
#undef LOAD_B
#undef WRITE_B
}

// ---------------------------------------------------------------------------
extern "C" void kernel_launch(void* const* d_in, const int* in_sizes, int n_in,
                              void* d_out, int out_size, void* d_ws, size_t ws_size,
                              hipStream_t stream)
{
  const float* emb   = (const float*)d_in[0];
  const float* Kg    = (const float*)d_in[1];
  const float* t_in  = (const float*)d_in[2];
  const int*   label = (const int*)d_in[3];

  float* out1 = (float*)d_out;                 // output * S   [512*100000]
  float* out2 = out1 + (size_t)B_M * C_N;      // origin * S   [512*100000]
  float* out3 = out1 + 2 * (size_t)B_M * C_N;  // scalar loss

  unsigned char* wsA = (unsigned char*)d_ws;   // 512KB swizzled bf16 A tiles
  float* tl   = (float*)((unsigned char*)d_ws + 524288);
  float* ctm  = tl + 512;
  float* ftl  = ctm + 512;
  float* tnew = ftl + 512;

  prep_kernel<<<512, 256, 0, stream>>>(emb, Kg, label, wsA, tl);
  finalize_kernel<<<1, 512, 0, stream>>>(tl, t_in, ctm, ftl, tnew, out3);
  int nb = 4 * 782;  // BN=128 -> 782 pids x 4 mq = 3128
  gemm_kernel<<<nb, 512, 0, stream>>>(Kg, wsA, ctm, ftl, label, tnew, out1, out2);
}

// Round 11
// 141.876 us; speedup vs baseline: 4.6162x; 1.3273x over previous
//
#include <hip/hip_runtime.h>
#include <hip/hip_bf16.h>
#include <stdint.h>

// Problem constants
#define B_M 512
#define D_K 512
#define C_N 100000
#define S_SCALE 64.0f
#define W_LOSS 0.003f
#define COS_M_C 0.79608379854905604f
#define SIN_M_C 0.60518640573603957f
#define THRESH_C (-0.79608379854905604f)
#define MM_C 0.39337116372842573f

typedef __bf16 bf16x8 __attribute__((ext_vector_type(8)));
typedef float f32x4 __attribute__((ext_vector_type(4)));

typedef const __attribute__((address_space(1))) unsigned char* gptr_t;
typedef __attribute__((address_space(3))) unsigned char* sptr_t;

__device__ __forceinline__ unsigned short f2bf(float f) {
  __bf16 h = (__bf16)f;
  return __builtin_bit_cast(unsigned short, h);
}

// ---------------------------------------------------------------------------
// Kernel 1: normalize emb rows (f32), write swizzled bf16 A-tiles to ws,
// compute target_logit[b] exactly in f32.
// wsA layout: 16 tiles (mhalf 0..1  x  ktile 0..7) of 32 KB;
// tile = [256 rows][128 B], byte-in-row XOR ((row&7)<<4)  (LDS image).
// ---------------------------------------------------------------------------
__global__ __launch_bounds__(256) void prep_kernel(
    const float* __restrict__ emb, const float* __restrict__ Kg,
    const int* __restrict__ label, unsigned char* __restrict__ wsA,
    float* __restrict__ tl)
{
  int b = blockIdx.x, t = threadIdx.x;
  __shared__ float row[512];
  __shared__ float r1[256], r2[256];

  float2 v = ((const float2*)(emb + (size_t)b * 512))[t];
  r1[t] = v.x * v.x + v.y * v.y;
  __syncthreads();
  for (int s = 128; s > 0; s >>= 1) {
    if (t < s) r1[t] += r1[t + s];
    __syncthreads();
  }
  float inv = 1.0f / sqrtf(r1[0]);
  float e0 = v.x * inv, e1 = v.y * inv;
  row[2 * t] = e0;
  row[2 * t + 1] = e1;

  {
    int mhalf = b >> 8, lrow = b & 255;
    int kk = t >> 5;  // (2t)/64 : k-tile index
    int byte_in = (4 * (t & 31)) ^ ((lrow & 7) << 4);
    ushort2 h;
    h.x = f2bf(e0);
    h.y = f2bf(e1);
    *(ushort2*)(wsA + (size_t)(mhalf * 8 + kk) * 32768 + lrow * 128 + byte_in) = h;
  }
  __syncthreads();

  int lab = label[b];
  const float* kc = Kg + lab;
  float dot = 0.f, csq = 0.f;
  for (int d = t; d < 512; d += 256) {
    float kv = kc[(size_t)d * C_N];
    dot += row[d] * kv;
    csq += kv * kv;
  }
  r1[t] = dot;
  r2[t] = csq;
  __syncthreads();
  for (int s = 128; s > 0; s >>= 1) {
    if (t < s) { r1[t] += r1[t + s]; r2[t] += r2[t + s]; }
    __syncthreads();
  }
  if (t == 0) {
    float tlv = r1[0] / sqrtf(r2[0]);
    tl[b] = fminf(1.f, fmaxf(-1.f, tlv));
  }
}

// ---------------------------------------------------------------------------
// Kernel 2: t_new, cos_theta_m[b], final_target_logit[b], center-loss scalar.
// ---------------------------------------------------------------------------
__global__ __launch_bounds__(512) void finalize_kernel(
    const float* __restrict__ tl, const float* __restrict__ t_in,
    float* __restrict__ ctm, float* __restrict__ ftl,
    float* __restrict__ tnew, float* __restrict__ out3)
{
  int t = threadIdx.x;
  float v = tl[t];
  __shared__ float r1[512], r2[512];
  float ac = acosf(v);
  r1[t] = v;
  r2[t] = ac * sqrtf(ac);  // acos^1.5
  __syncthreads();
  for (int s = 256; s > 0; s >>= 1) {
    if (t < s) { r1[t] += r1[t + s]; r2[t] += r2[t + s]; }
    __syncthreads();
  }
  if (t == 0) {
    tnew[0] = 0.99f * t_in[0] + 0.01f * (r1[0] / 512.0f);
    out3[0] = S_SCALE * W_LOSS * (r2[0] / 512.0f);
  }
  float st = sqrtf(fmaxf(0.f, 1.f - v * v));
  float cm = v * COS_M_C - st * SIN_M_C;
  ctm[t] = cm;
  ftl[t] = (v > THRESH_C) ? cm : (v - MM_C);
}

// ---------------------------------------------------------------------------
// Kernel 3: fused GEMM + epilogue. R4's deep pipeline at R7's winning tile.
// BM=256, BN=64, BK=64; 512 threads, 8 waves (2M x 4N), wave tile 128x16.
// A double-buffered LDS (2x32KB), gll prefetch 1 step ahead (L2-resident ws).
// B prefetched 2 steps ahead into register sets bf0/bf1 (B[j] in set j&1);
// per-step counted vmcnt(8) retires {B[k+1] regs, A[k+1] DMA} and keeps
// B[k+2] (8 newest) in flight -> B flight ~2 compute phases >= HBM latency.
// __launch_bounds__(512,2): spill-proof (R6/R8/R9 lesson, R10 verified).
// Epilogue: acc -> LDS (f32, XOR-swizzled) -> 256B-contiguous NT stores.
// ---------------------------------------------------------------------------
#define LDS_TOTAL 73728  // A dbuf [0,65536); B [65536,73728)
// params after last compute (B region dead): colpart @65536 (2048),
// invn @67584 (256), ctm @67840 (1024), ftl @68864 (1024), lab @69888 (1024)

__global__ __launch_bounds__(512, 2) void gemm_kernel(
    const float* __restrict__ Kg, const unsigned char* __restrict__ wsA,
    const float* __restrict__ ctm_g, const float* __restrict__ ftl_g,
    const int* __restrict__ label, const float* __restrict__ tnew_g,
    float* __restrict__ out1, float* __restrict__ out2)
{
  __shared__ __align__(16) unsigned char smem[LDS_TOTAL];

  int t = threadIdx.x;
  int lane = t & 63, wv = t >> 6;
  int wm = wv >> 2, wn = wv & 3;  // 2M x 4N
  int kq = lane >> 4, lr = lane & 15;

  // m204 bijective XCD swizzle: nwg=3126, q8=390, r8=6. mhalf pair (2p,2p+1)
  // contiguous on one XCD -> B panel L2 reuse across the pair.
  int bid = blockIdx.x;
  {
    int xcd = bid & 7, seq = bid >> 3;
    bid = (xcd < 6 ? xcd * 391 : 6 * 391 + (xcd - 6) * 390) + seq;
  }
  int pid = bid >> 1, mhalf = bid & 1;
  long c0 = (long)pid * 64;

  // B staging: thread owns column c (t&63), k-segment kseg (t>>6): 8 rows
  int c = t & 63, kseg = t >> 6;
  bool binb = (c0 + c) < C_N;
  const float* Bcol = Kg + c0 + c + (size_t)kseg * 8 * C_N;

  f32x4 acc[8] = {};
  float csq = 0.f;
  float bf0[8], bf1[8];  // B[j] lives in set (j&1)

  const unsigned char* wsTile = wsA + (size_t)mhalf * (8 * 32768);
  unsigned char* smemB = smem + 65536;
  unsigned char* browB = smemB + c * 128;

#define LOAD_B(dst, j)                                                       \
  {                                                                          \
    const float* src = Bcol + (size_t)((j) * 64) * C_N;                      \
    _Pragma("unroll") for (int i = 0; i < 8; ++i)                            \
        dst[i] = binb ? src[(size_t)i * C_N] : 0.f;                          \
  }

#define WRITE_B(src)                                                         \
  {                                                                          \
    _Pragma("unroll") for (int i = 0; i < 8; ++i) csq += src[i] * src[i];    \
    union { unsigned short u[8]; uint4 q; } pk;                              \
    _Pragma("unroll") for (int i = 0; i < 8; ++i) pk.u[i] = f2bf(src[i]);    \
    *(uint4*)(browB + ((kseg * 16) ^ ((c & 7) << 4))) = pk.q;                \
  }

  // ---- prologue: A[0] DMA -> buf0, B[0]/B[1] reg loads, B[0] -> LDS
  {
#pragma unroll
    for (int i = 0; i < 4; ++i) {
      int off = wv * 4096 + i * 1024;
      __builtin_amdgcn_global_load_lds((gptr_t)(wsTile + off + lane * 16),
                                       (sptr_t)(smem + off), 16, 0, 0);
    }
    __builtin_amdgcn_sched_barrier(0);
    LOAD_B(bf0, 0);
    __builtin_amdgcn_sched_barrier(0);
    LOAD_B(bf1, 1);
    __builtin_amdgcn_sched_barrier(0);
    asm volatile("s_waitcnt vmcnt(8)" ::: "memory");  // A[0]+B[0] done
    __builtin_amdgcn_sched_barrier(0);
    WRITE_B(bf0);
    __syncthreads();
  }

  // ---- main loop: 8 K-steps, fully unrolled (static reg-set selects)
#pragma unroll
  for (int kkt = 0; kkt < 8; ++kkt) {
    int cur = kkt & 1;
    if (kkt < 7) {
      // prefetch A[kkt+1] into the other buffer (DMA overlaps compute)
      const unsigned char* tA = wsTile + (size_t)(kkt + 1) * 32768;
#pragma unroll
      for (int i = 0; i < 4; ++i) {
        int off = wv * 4096 + i * 1024;
        __builtin_amdgcn_global_load_lds((gptr_t)(tA + off + lane * 16),
                                         (sptr_t)(smem + (cur ^ 1) * 32768 + off), 16, 0, 0);
      }
      __builtin_amdgcn_sched_barrier(0);
    }
    if (kkt < 6) {
      if (kkt & 1) { LOAD_B(bf1, kkt + 2); } else { LOAD_B(bf0, kkt + 2); }
      __builtin_amdgcn_sched_barrier(0);
    }

    // compute current buffers
    const unsigned char* Ab = smem + cur * 32768;
#pragma unroll
    for (int ks = 0; ks < 2; ++ks) {
      int kb = ks * 64 + kq * 16;
      int n = wn * 16 + lr;
      bf16x8 bfr = *(const bf16x8*)(smemB + n * 128 + (kb ^ ((n & 7) << 4)));
#pragma unroll
      for (int mf = 0; mf < 8; ++mf) {
        int m = wm * 128 + mf * 16 + lr;
        bf16x8 afr = *(const bf16x8*)(Ab + m * 128 + (kb ^ ((m & 7) << 4)));
        acc[mf] = __builtin_amdgcn_mfma_f32_16x16x32_bf16(afr, bfr, acc[mf], 0, 0, 0);
      }
    }

    // counted wait: retire {B[kkt+1] regs (8), A[kkt+1] DMA (4)}, keep
    // B[kkt+2] (8 newest) in flight across the barrier. Tail drains fully.
    if (kkt < 6) {
      asm volatile("s_waitcnt vmcnt(8)" ::: "memory");
    } else {
      asm volatile("s_waitcnt vmcnt(0)" ::: "memory");
    }
    __builtin_amdgcn_sched_barrier(0);
    __syncthreads();  // barrier-1: B-LDS reads done, A[kkt+1] landed

    if (kkt < 7) {
      if (kkt & 1) { WRITE_B(bf0); } else { WRITE_B(bf1); }
      __syncthreads();  // barrier-2: B[kkt+1] visible
    }
  }

  // ---- column norms + per-row params (B region dead)
  float* colpart = (float*)(smem + 65536);  // [8][64]
  float* invn    = (float*)(smem + 67584);  // [64]
  float* ctm_s   = (float*)(smem + 67840);  // [256]
  float* ftl_s   = (float*)(smem + 68864);  // [256]
  int*   lab_s   = (int*)  (smem + 69888);  // [256]
  colpart[t] = csq;
  if (t < 256) {
    ctm_s[t] = ctm_g[mhalf * 256 + t];
    ftl_s[t] = ftl_g[mhalf * 256 + t];
    lab_s[t] = label[mhalf * 256 + t];
  }
  __syncthreads();
  if (t < 64) {
    float s = 0.f;
#pragma unroll
    for (int g = 0; g < 8; ++g) s += colpart[g * 64 + t];
    invn[t] = 1.0f / sqrtf(fmaxf(s, 1e-30f));
  }
  __syncthreads();
  float tn = tnew_g[0];

  // ---- epilogue: 2 chunks of 128 rows; stage acc in LDS (aliases Abuf0,
  // barrier-separated from last compute on Abuf1), 256B-contiguous NT stores.
  for (int q = 0; q < 2; ++q) {
    if (wm == q) {
#pragma unroll
      for (int mf = 0; mf < 8; ++mf) {
#pragma unroll
        for (int j = 0; j < 4; ++j) {
          int row = mf * 16 + kq * 4 + j;  // [0,128)
          int col = wn * 16 + lr;          // [0,64)
          *(float*)(smem + row * 256 + ((col * 4) ^ (((row >> 2) & 3) << 6))) =
              acc[mf][j];
        }
      }
    }
    __syncthreads();
#pragma unroll
    for (int rr = 0; rr < 4; ++rr) {
      int row = rr * 32 + (t >> 4);   // [0,128)
      int cb = (t & 15) * 4;          // col base [0,64)
      f32x4 v = *(const f32x4*)(smem + row * 256 + ((cb * 4) ^ (((row >> 2) & 3) << 6)));
      long cgs = c0 + cb;
      if (cgs < C_N) {  // group fully valid (C_N % 4 == 0)
        int lrow = q * 128 + row;
        float cm = ctm_s[lrow], fl = ftl_s[lrow];
        int lb = lab_s[lrow];
        f32x4 iv = *(const f32x4*)(invn + cb);
        f32x4 o1v, o2v;
#pragma unroll
        for (int jj = 0; jj < 4; ++jj) {
          float cosv = fminf(1.f, fmaxf(-1.f, v[jj] * iv[jj]));
          o2v[jj] = cosv * S_SCALE;
          float ct = (cosv > cm) ? cosv * (tn + cosv) : cosv;
          if (lb == (int)(cgs + jj)) ct = fl;
          o1v[jj] = ct * S_SCALE;
        }
        size_t idx = (size_t)(mhalf * 256 + lrow) * C_N + cgs;
        __builtin_nontemporal_store(o1v, (f32x4*)(out1 + idx));
        __builtin_nontemporal_store(o2v, (f32x4*)(out2 + idx));
      }
    }
    __syncthreads();
  }
#undef LOAD_B
#undef WRITE_B
}

// ---------------------------------------------------------------------------
extern "C" void kernel_launch(void* const* d_in, const int* in_sizes, int n_in,
                              void* d_out, int out_size, void* d_ws, size_t ws_size,
                              hipStream_t stream)
{
  const float* emb   = (const float*)d_in[0];
  const float* Kg    = (const float*)d_in[1];
  const float* t_in  = (const float*)d_in[2];
  const int*   label = (const int*)d_in[3];

  float* out1 = (float*)d_out;                 // output * S   [512*100000]
  float* out2 = out1 + (size_t)B_M * C_N;      // origin * S   [512*100000]
  float* out3 = out1 + 2 * (size_t)B_M * C_N;  // scalar loss

  unsigned char* wsA = (unsigned char*)d_ws;   // 512KB swizzled bf16 A tiles
  float* tl   = (float*)((unsigned char*)d_ws + 524288);
  float* ctm  = tl + 512;
  float* ftl  = ctm + 512;
  float* tnew = ftl + 512;

  prep_kernel<<<512, 256, 0, stream>>>(emb, Kg, label, wsA, tl);
  finalize_kernel<<<1, 512, 0, stream>>>(tl, t_in, ctm, ftl, tnew, out3);
  int nb = 2 * 1563;  // BN=64 -> 1563 pids x 2 mhalf = 3126
  gemm_kernel<<<nb, 512, 0, stream>>>(Kg, wsA, ctm, ftl, label, tnew, out1, out2);
}